// Round 8
// baseline (130.083 us; speedup 1.0000x reference)
//
#include <hip/hip_runtime.h>
#include <hip/hip_cooperative_groups.h>

namespace cg = cooperative_groups;

#define MM 256
#define PP 2097152            // fixed pair-list length
#define RCF 5.0f
#define NBLK 512              // 128 structures x 4 row-blocks
#define GTH (NBLK * 256)
#define CAP 2048              // staged pairs per flush batch

typedef unsigned long long u64;

// ws layout: masks u64[GTH] (fallback only) | bsums int[NBLK] | partials float[3*128]

__device__ inline void wave_min3(float& x, float& y, float& z) {
    #pragma unroll
    for (int off = 32; off > 0; off >>= 1) {
        x = fminf(x, __shfl_xor(x, off, 64));
        y = fminf(y, __shfl_xor(y, off, 64));
        z = fminf(z, __shfl_xor(z, off, 64));
    }
}

__device__ inline void reduce_min128(const float* __restrict__ partials,
                                     float& mnx, float& mny, float& mnz) {
    const int lane = threadIdx.x & 63;
    float x = fminf(partials[3 * lane + 0], partials[3 * (lane + 64) + 0]);
    float y = fminf(partials[3 * lane + 1], partials[3 * (lane + 64) + 1]);
    float z = fminf(partials[3 * lane + 2], partials[3 * (lane + 64) + 2]);
    wave_min3(x, y, z);
    mnx = x; mny = y; mnz = z;
}

__device__ inline void zero_range(float* __restrict__ o, int lo, int hi, int g) {
    int a = (lo + 3) & ~3;           // hi is always a multiple of 4
    if (a > hi) a = hi;
    if (g < a - lo) o[lo + g] = 0.0f;
    float4* o4 = reinterpret_cast<float4*>(o);
    const float4 z4 = make_float4(0.f, 0.f, 0.f, 0.f);
    for (int q = (a >> 2) + g; q < (hi >> 2); q += GTH) o4[q] = z4;
}

// ---------------------------------------------------------------------------
// Geometry: block b2 = b*4 + rblk owns rows rblk*64..+64 of structure b;
// thread t = i_loc*4 + c handles (row i_loc, j-chunk c); global slot
// b2*256+t is lexicographic in (b,i,j). Tiles padded [4][65] (bank-spread).
// fp32 replicates reference exactly: pos=coord-min (rn sub), diff=pos_j-pos_i,
// sq=((dx*dx+dy*dy)+dz*dz) no-FMA, dist=rn sqrt, mask=(sq>0)&(dist<5).
// ---------------------------------------------------------------------------

// ============================ fused cooperative =============================
__global__ void __launch_bounds__(256, 2)
fused_k(const float* __restrict__ coord, float* __restrict__ partials,
        int* __restrict__ bsums, float* __restrict__ outF) {
    cg::grid_group grid = cg::this_grid();
    const int b2 = blockIdx.x;
    const int b = b2 >> 2, rblk = b2 & 3;
    const int t = threadIdx.x;
    const int lane = t & 63, w = t >> 6;

    __shared__ float sx[4][65], sy[4][65], sz[4][65];
    __shared__ float lmin[3][4];
    __shared__ int wsum[4];
    __shared__ int pre[NBLK];
    __shared__ int sTot;
    __shared__ float sd[CAP];        // dist plane
    __shared__ float sind[2 * CAP];  // {gi,gj} plane (as float)
    __shared__ float sdf[3 * CAP];   // {dx,dy,dz} plane

    // Phase A: blocks 0..127 reduce their 256 atoms -> partials[128][3]
    if (b2 < 128) {
        const int g = b2 * 256 + t;
        float x = coord[3 * g + 0], y = coord[3 * g + 1], z = coord[3 * g + 2];
        wave_min3(x, y, z);
        if (lane == 0) { lmin[0][w] = x; lmin[1][w] = y; lmin[2][w] = z; }
        __syncthreads();
        if (t == 0) {
            partials[3 * b2 + 0] = fminf(fminf(lmin[0][0], lmin[0][1]), fminf(lmin[0][2], lmin[0][3]));
            partials[3 * b2 + 1] = fminf(fminf(lmin[1][0], lmin[1][1]), fminf(lmin[1][2], lmin[1][3]));
            partials[3 * b2 + 2] = fminf(fminf(lmin[2][0], lmin[2][1]), fminf(lmin[2][2], lmin[2][3]));
        }
    }
    grid.sync();

    float mnx, mny, mnz;
    reduce_min128(partials, mnx, mny, mnz);

    // Phase B: load structure tile, count + hit bitmask (kept in registers)
    const int ja = b * MM + t;
    sx[w][lane] = __fsub_rn(coord[3 * ja + 0], mnx);
    sy[w][lane] = __fsub_rn(coord[3 * ja + 1], mny);
    sz[w][lane] = __fsub_rn(coord[3 * ja + 2], mnz);
    __syncthreads();

    const int i_loc = t >> 2, c = t & 3;
    const float pix = sx[rblk][i_loc], piy = sy[rblk][i_loc], piz = sz[rblk][i_loc];
    u64 mask = 0ULL;
    for (int jj = 0; jj < 64; ++jj) {
        float dx = __fsub_rn(sx[c][jj], pix);
        float dy = __fsub_rn(sy[c][jj], piy);
        float dz = __fsub_rn(sz[c][jj], piz);
        float sq = __fadd_rn(__fadd_rn(__fmul_rn(dx, dx), __fmul_rn(dy, dy)),
                             __fmul_rn(dz, dz));
        if (sq > 0.0f && __fsqrt_rn(sq) < RCF) mask |= (1ULL << jj);
    }
    const int cnt = __popcll(mask);
    int incl = cnt;
    #pragma unroll
    for (int off = 1; off < 64; off <<= 1) {
        int v = __shfl_up(incl, off, 64);
        if (lane >= off) incl += v;
    }
    if (lane == 63) wsum[w] = incl;
    __syncthreads();
    const int agg = wsum[0] + wsum[1] + wsum[2] + wsum[3];
    int woff = 0;
    for (int k = 0; k < w; ++k) woff += wsum[k];
    const int lexcl = woff + incl - cnt;
    if (t == 0) bsums[b2] = agg;
    grid.sync();

    // Phase C: wave-0 register scan of the 512 block sums (1 barrier)
    if (w == 0) {
        int v[8]; int s = 0;
        #pragma unroll
        for (int q = 0; q < 8; ++q) { v[q] = bsums[lane * 8 + q]; s += v[q]; }
        int isum = s;
        #pragma unroll
        for (int off = 1; off < 64; off <<= 1) {
            int u = __shfl_up(isum, off, 64);
            if (lane >= off) isum += u;
        }
        int run = isum - s;                       // exclusive prefix, lane-major
        #pragma unroll
        for (int q = 0; q < 8; ++q) { pre[lane * 8 + q] = run; run += v[q]; }
        if (lane == 63) sTot = run;               // grand total
    }
    __syncthreads();
    const int base = pre[b2];
    const int total = (sTot < PP) ? sTot : PP;

    // staged, fully-coalesced emission
    const int gi = b * MM + rblk * 64 + i_loc;
    const int gj0 = b * MM + c * 64;
    const int nbat = (agg + CAP - 1) / CAP;
    for (int bb = 0; bb < nbat; ++bb) {
        const int wlo = bb * CAP, whi = wlo + CAP;
        int q = lexcl;
        u64 mm = mask;
        while (mm) {
            const int jj = __ffsll((long long)mm) - 1;
            mm &= mm - 1;
            if (q >= whi) break;
            if (q >= wlo) {
                float dx = __fsub_rn(sx[c][jj], pix);
                float dy = __fsub_rn(sy[c][jj], piy);
                float dz = __fsub_rn(sz[c][jj], piz);
                float sq = __fadd_rn(__fadd_rn(__fmul_rn(dx, dx), __fmul_rn(dy, dy)),
                                     __fmul_rn(dz, dz));
                const int s = q - wlo;
                sd[s] = __fsqrt_rn(sq);
                sind[2 * s + 0] = (float)gi;
                sind[2 * s + 1] = (float)(gj0 + jj);
                sdf[3 * s + 0] = dx;
                sdf[3 * s + 1] = dy;
                sdf[3 * s + 2] = dz;
            }
            q++;
        }
        __syncthreads();
        const int nq = ((agg - wlo) < CAP) ? (agg - wlo) : CAP;
        const int pbase = base + wlo;
        int rem = PP - pbase; if (rem < 0) rem = 0;
        const int nv = (nq < rem) ? nq : rem;
        for (int k = t; k < nv; k += 256)     outF[2 * PP + pbase + k]     = sd[k];
        for (int k = t; k < 2 * nv; k += 256) outF[2 * pbase + k]          = sind[k];
        for (int k = t; k < 3 * nv; k += 256) outF[3 * PP + 3 * pbase + k] = sdf[k];
        __syncthreads();
    }

    // tail zeroing (disjoint from pair region; coalesced float4)
    const int g = b2 * 256 + t;
    zero_range(outF, 2 * total,          2 * PP, g);
    zero_range(outF, 2 * PP + total,     3 * PP, g);
    zero_range(outF, 3 * PP + 3 * total, 6 * PP, g);
}

// ======================= fallback (proven round-7 path) =====================
__global__ void __launch_bounds__(256)
min_k(const float* __restrict__ coord, float* __restrict__ partials) {
    const int g = blockIdx.x * 256 + threadIdx.x;
    float x = coord[3 * g + 0], y = coord[3 * g + 1], z = coord[3 * g + 2];
    wave_min3(x, y, z);
    __shared__ float lx[4], ly[4], lz[4];
    const int w = threadIdx.x >> 6;
    if ((threadIdx.x & 63) == 0) { lx[w] = x; ly[w] = y; lz[w] = z; }
    __syncthreads();
    if (threadIdx.x == 0) {
        partials[3 * blockIdx.x + 0] = fminf(fminf(lx[0], lx[1]), fminf(lx[2], lx[3]));
        partials[3 * blockIdx.x + 1] = fminf(fminf(ly[0], ly[1]), fminf(ly[2], ly[3]));
        partials[3 * blockIdx.x + 2] = fminf(fminf(lz[0], lz[1]), fminf(lz[2], lz[3]));
    }
}

__global__ void __launch_bounds__(256)
count_k(const float* __restrict__ coord, const float* __restrict__ partials,
        u64* __restrict__ masks, int* __restrict__ bsums) {
    const int b2 = blockIdx.x;
    const int b = b2 >> 2, rblk = b2 & 3;
    const int t = threadIdx.x;
    const int lane = t & 63, w = t >> 6;
    float mnx, mny, mnz;
    reduce_min128(partials, mnx, mny, mnz);

    __shared__ float sx[4][65], sy[4][65], sz[4][65];
    __shared__ int wsum[4];
    const int ja = b * MM + t;
    sx[w][lane] = __fsub_rn(coord[3 * ja + 0], mnx);
    sy[w][lane] = __fsub_rn(coord[3 * ja + 1], mny);
    sz[w][lane] = __fsub_rn(coord[3 * ja + 2], mnz);
    __syncthreads();

    const int i_loc = t >> 2, c = t & 3;
    const float pix = sx[rblk][i_loc], piy = sy[rblk][i_loc], piz = sz[rblk][i_loc];
    u64 m = 0ULL;
    for (int jj = 0; jj < 64; ++jj) {
        float dx = __fsub_rn(sx[c][jj], pix);
        float dy = __fsub_rn(sy[c][jj], piy);
        float dz = __fsub_rn(sz[c][jj], piz);
        float sq = __fadd_rn(__fadd_rn(__fmul_rn(dx, dx), __fmul_rn(dy, dy)),
                             __fmul_rn(dz, dz));
        if (sq > 0.0f && __fsqrt_rn(sq) < RCF) m |= (1ULL << jj);
    }
    masks[b2 * 256 + t] = m;
    int v = __popcll(m);
    #pragma unroll
    for (int off = 32; off > 0; off >>= 1) v += __shfl_xor(v, off, 64);
    if (lane == 0) wsum[w] = v;
    __syncthreads();
    if (t == 0) bsums[b2] = wsum[0] + wsum[1] + wsum[2] + wsum[3];
}

__global__ void __launch_bounds__(256)
write_k(const float* __restrict__ coord, const float* __restrict__ partials,
        const u64* __restrict__ masks, const int* __restrict__ bsums,
        float* __restrict__ outF) {
    const int b2 = blockIdx.x;
    const int b = b2 >> 2, rblk = b2 & 3;
    const int t = threadIdx.x;
    const int lane = t & 63, w = t >> 6;
    float mnx, mny, mnz;
    reduce_min128(partials, mnx, mny, mnz);

    __shared__ float sx[4][65], sy[4][65], sz[4][65];
    __shared__ int pre[NBLK];
    __shared__ int sTot;
    __shared__ int wsum[4];
    __shared__ float sd[CAP];
    __shared__ float sind[2 * CAP];
    __shared__ float sdf[3 * CAP];

    const int ja = b * MM + t;
    sx[w][lane] = __fsub_rn(coord[3 * ja + 0], mnx);
    sy[w][lane] = __fsub_rn(coord[3 * ja + 1], mny);
    sz[w][lane] = __fsub_rn(coord[3 * ja + 2], mnz);

    if (w == 0) {                      // wave-0 register scan of 512 bsums
        int v[8]; int s = 0;
        #pragma unroll
        for (int q = 0; q < 8; ++q) { v[q] = bsums[lane * 8 + q]; s += v[q]; }
        int isum = s;
        #pragma unroll
        for (int off = 1; off < 64; off <<= 1) {
            int u = __shfl_up(isum, off, 64);
            if (lane >= off) isum += u;
        }
        int run = isum - s;
        #pragma unroll
        for (int q = 0; q < 8; ++q) { pre[lane * 8 + q] = run; run += v[q]; }
        if (lane == 63) sTot = run;
    }
    __syncthreads();
    const int base = pre[b2];
    const int total = (sTot < PP) ? sTot : PP;

    const u64 mask = masks[b2 * 256 + t];
    const int cnt = __popcll(mask);
    int incl = cnt;
    #pragma unroll
    for (int off = 1; off < 64; off <<= 1) {
        int v = __shfl_up(incl, off, 64);
        if (lane >= off) incl += v;
    }
    if (lane == 63) wsum[w] = incl;
    __syncthreads();
    const int agg = wsum[0] + wsum[1] + wsum[2] + wsum[3];
    int woff = 0;
    for (int k = 0; k < w; ++k) woff += wsum[k];
    const int lexcl = woff + incl - cnt;

    const int i_loc = t >> 2, c = t & 3;
    const float pix = sx[rblk][i_loc], piy = sy[rblk][i_loc], piz = sz[rblk][i_loc];
    const int gi = b * MM + rblk * 64 + i_loc;
    const int gj0 = b * MM + c * 64;

    const int nbat = (agg + CAP - 1) / CAP;
    for (int bb = 0; bb < nbat; ++bb) {
        const int wlo = bb * CAP, whi = wlo + CAP;
        int q = lexcl;
        u64 mm = mask;
        while (mm) {
            const int jj = __ffsll((long long)mm) - 1;
            mm &= mm - 1;
            if (q >= whi) break;
            if (q >= wlo) {
                float dx = __fsub_rn(sx[c][jj], pix);
                float dy = __fsub_rn(sy[c][jj], piy);
                float dz = __fsub_rn(sz[c][jj], piz);
                float sq = __fadd_rn(__fadd_rn(__fmul_rn(dx, dx), __fmul_rn(dy, dy)),
                                     __fmul_rn(dz, dz));
                const int s = q - wlo;
                sd[s] = __fsqrt_rn(sq);
                sind[2 * s + 0] = (float)gi;
                sind[2 * s + 1] = (float)(gj0 + jj);
                sdf[3 * s + 0] = dx;
                sdf[3 * s + 1] = dy;
                sdf[3 * s + 2] = dz;
            }
            q++;
        }
        __syncthreads();
        const int nq = ((agg - wlo) < CAP) ? (agg - wlo) : CAP;
        const int pbase = base + wlo;
        int rem = PP - pbase; if (rem < 0) rem = 0;
        const int nv = (nq < rem) ? nq : rem;
        for (int k = t; k < nv; k += 256)     outF[2 * PP + pbase + k]     = sd[k];
        for (int k = t; k < 2 * nv; k += 256) outF[2 * pbase + k]          = sind[k];
        for (int k = t; k < 3 * nv; k += 256) outF[3 * PP + 3 * pbase + k] = sdf[k];
        __syncthreads();
    }

    const int g = b2 * 256 + t;
    zero_range(outF, 2 * total,          2 * PP, g);
    zero_range(outF, 2 * PP + total,     3 * PP, g);
    zero_range(outF, 3 * PP + 3 * total, 6 * PP, g);
}

extern "C" void kernel_launch(void* const* d_in, const int* in_sizes, int n_in,
                              void* d_out, int out_size, void* d_ws, size_t ws_size,
                              hipStream_t stream) {
    const float* coord = (const float*)d_in[0];
    // d_in[1] (ind_1) structurally encoded (B contiguous blocks of M); unused.
    float* outF = (float*)d_out;

    u64*   masks    = (u64*)d_ws;                          // fallback only
    int*   bsums    = (int*)(masks + GTH);                 // 512 ints
    float* partials = (float*)(bsums + NBLK);              // 384 floats

    void* args[] = { (void*)&coord, (void*)&partials, (void*)&bsums, (void*)&outF };
    hipError_t e = hipLaunchCooperativeKernel((const void*)fused_k, dim3(NBLK),
                                              dim3(256), args, 0u, stream);
    if (e != hipSuccess) {
        // Same math, same output: proven 3-kernel path.
        min_k  <<<128,  256, 0, stream>>>(coord, partials);
        count_k<<<NBLK, 256, 0, stream>>>(coord, partials, masks, bsums);
        write_k<<<NBLK, 256, 0, stream>>>(coord, partials, masks, bsums, outF);
    }
}

// Round 9
// 59.169 us; speedup vs baseline: 2.1985x; 2.1985x over previous
//
#include <hip/hip_runtime.h>

#define MM 256
#define PP 2097152            // fixed pair-list length
#define NBLK 512              // 128 structures x 4 row-blocks
#define GTH (NBLK * 256)
#define CAP 2048              // staged pairs per flush batch
// Largest fp32 sq with rn(sqrt(sq)) < 5.0f  (== 25 - 2*ulp(25); proven exact)
#define SQMAX 24.999996185302734375f

typedef unsigned long long u64;

// ws layout: flags u64[NBLK] | tot u64[1] | partials float[3*128]
// flags[i]: (state<<32)|value; state 0=invalid, 1=aggregate, 2=inclusive prefix.

__device__ inline void wave_min3(float& x, float& y, float& z) {
    #pragma unroll
    for (int off = 32; off > 0; off >>= 1) {
        x = fminf(x, __shfl_xor(x, off, 64));
        y = fminf(y, __shfl_xor(y, off, 64));
        z = fminf(z, __shfl_xor(z, off, 64));
    }
}

// ---------------------------------------------------------------------------
// K1: per-block (256-atom) coord minima -> partials[128][3]; zero lookback
// flags + tot (fresh every call; deterministic, graph-safe).
// ---------------------------------------------------------------------------
__global__ void __launch_bounds__(256)
min_k(const float* __restrict__ coord, float* __restrict__ partials,
      u64* __restrict__ flags) {
    const int g = blockIdx.x * 256 + threadIdx.x;
    if (g < NBLK + 1) flags[g] = 0ULL;
    float x = coord[3 * g + 0], y = coord[3 * g + 1], z = coord[3 * g + 2];
    wave_min3(x, y, z);
    __shared__ float lx[4], ly[4], lz[4];
    const int w = threadIdx.x >> 6;
    if ((threadIdx.x & 63) == 0) { lx[w] = x; ly[w] = y; lz[w] = z; }
    __syncthreads();
    if (threadIdx.x == 0) {
        partials[3 * blockIdx.x + 0] = fminf(fminf(lx[0], lx[1]), fminf(lx[2], lx[3]));
        partials[3 * blockIdx.x + 1] = fminf(fminf(ly[0], ly[1]), fminf(ly[2], ly[3]));
        partials[3 * blockIdx.x + 2] = fminf(fminf(lz[0], lz[1]), fminf(lz[2], lz[3]));
    }
}

__device__ inline void reduce_min128(const float* __restrict__ partials,
                                     float& mnx, float& mny, float& mnz) {
    const int lane = threadIdx.x & 63;
    float x = fminf(partials[3 * lane + 0], partials[3 * (lane + 64) + 0]);
    float y = fminf(partials[3 * lane + 1], partials[3 * (lane + 64) + 1]);
    float z = fminf(partials[3 * lane + 2], partials[3 * (lane + 64) + 2]);
    wave_min3(x, y, z);
    mnx = x; mny = y; mnz = z;
}

__device__ inline void zero_range(float* __restrict__ o, int lo, int hi, int g) {
    int a = (lo + 3) & ~3;           // hi is always a multiple of 4
    if (a > hi) a = hi;
    if (g < a - lo) o[lo + g] = 0.0f;
    float4* o4 = reinterpret_cast<float4*>(o);
    const float4 z4 = make_float4(0.f, 0.f, 0.f, 0.f);
    for (int q = (a >> 2) + g; q < (hi >> 2); q += GTH) o4[q] = z4;
}

// ---------------------------------------------------------------------------
// K2 (fused): count (mask in regs) -> decoupled-lookback base (no grid
// barrier!) -> staged coalesced emit -> tail zero (tot published before
// emission, so the end read is a non-spinning load in practice).
// Geometry: block b2 = b*4+rblk owns rows rblk*64..+64 of structure b;
// thread t = i_loc*4+c handles (row i_loc, j-chunk c); slot b2*256+t is
// lexicographic in (b,i,j). Tile [4][65] float4 {x,y,z,0}: chunk bases on
// disjoint bank quads. fp32 replicates reference exactly: pos=coord-min (rn
// sub), diff=pos_j-pos_i, sq=((dx*dx+dy*dy)+dz*dz) no-FMA; membership via
// sq<=SQMAX (== rn(sqrt(sq))<5 exactly); d=rn sqrt for hits only.
// ---------------------------------------------------------------------------
__global__ void __launch_bounds__(256)
fused2_k(const float* __restrict__ coord, const float* __restrict__ partials,
         u64* __restrict__ flags, u64* __restrict__ tot,
         float* __restrict__ outF) {
    const int b2 = blockIdx.x;
    const int b = b2 >> 2, rblk = b2 & 3;
    const int t = threadIdx.x;
    const int lane = t & 63, w = t >> 6;

    __shared__ float4 tile4[4][65];
    __shared__ int wsum[4];
    __shared__ int sBase, sTot;
    __shared__ float sd[CAP];        // dist plane
    __shared__ float sind[2 * CAP];  // {gi,gj} plane (as float)
    __shared__ float sdf[3 * CAP];   // {dx,dy,dz} plane

    float mnx, mny, mnz;
    reduce_min128(partials, mnx, mny, mnz);

    const int ja = b * MM + t;
    tile4[w][lane] = make_float4(__fsub_rn(coord[3 * ja + 0], mnx),
                                 __fsub_rn(coord[3 * ja + 1], mny),
                                 __fsub_rn(coord[3 * ja + 2], mnz), 0.0f);
    __syncthreads();

    const int i_loc = t >> 2, c = t & 3;
    const float4 pi4 = tile4[rblk][i_loc];
    const float pix = pi4.x, piy = pi4.y, piz = pi4.z;

    // count + hit bitmask (registers only)
    u64 mask = 0ULL;
    for (int jj = 0; jj < 64; ++jj) {
        float4 v = tile4[c][jj];
        float dx = __fsub_rn(v.x, pix);
        float dy = __fsub_rn(v.y, piy);
        float dz = __fsub_rn(v.z, piz);
        float sq = __fadd_rn(__fadd_rn(__fmul_rn(dx, dx), __fmul_rn(dy, dy)),
                             __fmul_rn(dz, dz));
        if (sq > 0.0f && sq <= SQMAX) mask |= (1ULL << jj);
    }
    const int cnt = __popcll(mask);
    int incl = cnt;
    #pragma unroll
    for (int off = 1; off < 64; off <<= 1) {
        int v = __shfl_up(incl, off, 64);
        if (lane >= off) incl += v;
    }
    if (lane == 63) wsum[w] = incl;
    __syncthreads();
    const int agg = wsum[0] + wsum[1] + wsum[2] + wsum[3];
    int woff = 0;
    for (int k = 0; k < w; ++k) woff += wsum[k];
    const int lexcl = woff + incl - cnt;

    // publish aggregate so successors can progress
    if (t == 0)
        __hip_atomic_store(&flags[b2], (1ULL << 32) | (unsigned)agg,
                           __ATOMIC_RELEASE, __HIP_MEMORY_SCOPE_AGENT);

    // wave-parallel decoupled lookback (wave 0 only; waits on predecessors only)
    if (w == 0) {
        long long acc = 0;
        int look = b2 - 1;
        while (look >= 0) {
            const int idx = look - lane;
            u64 s = (idx >= 0)
                ? __hip_atomic_load(&flags[idx], __ATOMIC_ACQUIRE,
                                    __HIP_MEMORY_SCOPE_AGENT)
                : (2ULL << 32);                    // virtual block -1: prefix 0
            const unsigned f = (unsigned)(s >> 32);
            const int v = (int)(unsigned)s;
            const u64 bal0 = __ballot(f == 0u);
            const u64 bal2 = __ballot(f == 2u);
            const int k2 = bal2 ? (__ffsll(bal2) - 1) : 64;
            const u64 below = (k2 >= 64) ? ~0ULL : ((1ULL << k2) - 1ULL);
            if ((bal0 & below) == 0ULL) {
                int contrib = (k2 >= 64) ? v : ((lane <= (unsigned)k2) ? v : 0);
                #pragma unroll
                for (int off = 32; off > 0; off >>= 1)
                    contrib += __shfl_xor(contrib, off, 64);
                acc += contrib;
                if (k2 < 64) break;                // hit an inclusive prefix
                look -= 64;                        // whole window was aggregates
            } else {
                __builtin_amdgcn_s_sleep(1);       // back off, reduce L2 hammer
            }
        }
        if (lane == 0) sBase = (int)acc;
    }
    __syncthreads();
    const int base = sBase;

    // publish inclusive prefix; last block publishes grand total
    if (t == 0) {
        __hip_atomic_store(&flags[b2], (2ULL << 32) | (unsigned)(base + agg),
                           __ATOMIC_RELEASE, __HIP_MEMORY_SCOPE_AGENT);
        if (b2 == NBLK - 1)
            __hip_atomic_store(tot, (1ULL << 32) | (unsigned)(base + agg),
                               __ATOMIC_RELEASE, __HIP_MEMORY_SCOPE_AGENT);
    }

    // staged, fully-coalesced emission
    const int gi = b * MM + rblk * 64 + i_loc;
    const int gj0 = b * MM + c * 64;
    const int nbat = (agg + CAP - 1) / CAP;
    for (int bb = 0; bb < nbat; ++bb) {
        const int wlo = bb * CAP, whi = wlo + CAP;
        int q = lexcl;
        u64 mm = mask;
        while (mm) {
            const int jj = __ffsll((long long)mm) - 1;
            mm &= mm - 1;
            if (q >= whi) break;
            if (q >= wlo) {
                float4 v = tile4[c][jj];
                float dx = __fsub_rn(v.x, pix);
                float dy = __fsub_rn(v.y, piy);
                float dz = __fsub_rn(v.z, piz);
                float sq = __fadd_rn(__fadd_rn(__fmul_rn(dx, dx), __fmul_rn(dy, dy)),
                                     __fmul_rn(dz, dz));
                const int s = q - wlo;
                sd[s] = __fsqrt_rn(sq);
                sind[2 * s + 0] = (float)gi;
                sind[2 * s + 1] = (float)(gj0 + jj);
                sdf[3 * s + 0] = dx;
                sdf[3 * s + 1] = dy;
                sdf[3 * s + 2] = dz;
            }
            q++;
        }
        __syncthreads();
        const int nq = ((agg - wlo) < CAP) ? (agg - wlo) : CAP;
        const int pbase = base + wlo;
        int rem = PP - pbase; if (rem < 0) rem = 0;
        const int nv = (nq < rem) ? nq : rem;
        for (int k = t; k < nv; k += 256)     outF[2 * PP + pbase + k]     = sd[k];
        for (int k = t; k < 2 * nv; k += 256) outF[2 * pbase + k]          = sind[k];
        for (int k = t; k < 3 * nv; k += 256) outF[3 * PP + 3 * pbase + k] = sdf[k];
        __syncthreads();
    }

    // grand total (published before any emission finished -> no real spin)
    if (t == 0) {
        u64 s;
        while (((s = __hip_atomic_load(tot, __ATOMIC_ACQUIRE,
                                       __HIP_MEMORY_SCOPE_AGENT)) >> 32) == 0ULL)
            __builtin_amdgcn_s_sleep(8);
        sTot = (int)(unsigned)s;
    }
    __syncthreads();
    const int total = (sTot < PP) ? sTot : PP;

    // tail zeroing (disjoint from pair region; coalesced float4)
    const int g = b2 * 256 + t;
    zero_range(outF, 2 * total,          2 * PP, g);
    zero_range(outF, 2 * PP + total,     3 * PP, g);
    zero_range(outF, 3 * PP + 3 * total, 6 * PP, g);
}

extern "C" void kernel_launch(void* const* d_in, const int* in_sizes, int n_in,
                              void* d_out, int out_size, void* d_ws, size_t ws_size,
                              hipStream_t stream) {
    const float* coord = (const float*)d_in[0];
    // d_in[1] (ind_1) structurally encoded (B contiguous blocks of M); unused.
    float* outF = (float*)d_out;

    u64*   flags    = (u64*)d_ws;                  // [NBLK] + tot at [NBLK]
    u64*   tot      = flags + NBLK;
    float* partials = (float*)(flags + NBLK + 1);  // 384 floats

    min_k   <<<128,  256, 0, stream>>>(coord, partials, flags);
    fused2_k<<<NBLK, 256, 0, stream>>>(coord, partials, flags, tot, outF);
}

// Round 12
// 31.256 us; speedup vs baseline: 4.1619x; 1.8930x over previous
//
#include <hip/hip_runtime.h>
#include <float.h>

#define MM 256
#define PP 2097152            // fixed pair-list length
#define NBLK 512              // 128 structures x 4 row-blocks
#define GTH (NBLK * 256)
#define CAP 2048              // staged pairs per flush batch
// Largest fp32 sq with rn(sqrt(sq)) < 5.0f  (== 25 - 2*ulp(25); boundary-exact)
#define SQMAX 24.999996185302734375f

typedef unsigned long long u64;

// ws layout: masks u64[GTH] | bsums int[NBLK] | minvec float[3]

__device__ inline void wave_min3(float& x, float& y, float& z) {
    #pragma unroll
    for (int off = 32; off > 0; off >>= 1) {
        x = fminf(x, __shfl_xor(x, off, 64));
        y = fminf(y, __shfl_xor(y, off, 64));
        z = fminf(z, __shfl_xor(z, off, 64));
    }
}

__device__ inline void zero_range(float* __restrict__ o, int lo, int hi, int g) {
    int a = (lo + 3) & ~3;           // hi is always a multiple of 4
    if (a > hi) a = hi;
    if (g < a - lo) o[lo + g] = 0.0f;
    float4* o4 = reinterpret_cast<float4*>(o);
    const float4 z4 = make_float4(0.f, 0.f, 0.f, 0.f);
    for (int q = (a >> 2) + g; q < (hi >> 2); q += GTH) o4[q] = z4;
}

// ---------------------------------------------------------------------------
// Geometry: block b2 = b*4+rblk owns rows rblk*64..+64 of structure b; thread
// t = i_loc*4+c handles (row i_loc, j-chunk c); slot b2*256+t is lexicographic
// in (b,i,j). fp32 replicates the reference exactly: pos=coord-min (rn sub),
// diff=pos_j-pos_i, sq=((dx*dx+dy*dy)+dz*dz) no-FMA; membership sq<=SQMAX
// (== rn(sqrt(sq))<5 exactly); d=rn(sqrt) for hits only. fmin is exact and
// order-independent, so any reduction order matches jnp.min bitwise.
// ---------------------------------------------------------------------------

// K1: redundant per-block GLOBAL coordinate min (all 32768 atoms; coords are
// L2-resident so this replaces a kernel launch + boundary with ~L2 reads),
// then count: hit bitmask -> masks[], block totals -> bsums[]. Block 0
// publishes minvec for K2.
__global__ void __launch_bounds__(256)
count_k(const float* __restrict__ coord, float* __restrict__ minvec,
        u64* __restrict__ masks, int* __restrict__ bsums) {
    const int b2 = blockIdx.x;
    const int b = b2 >> 2, rblk = b2 & 3;
    const int t = threadIdx.x;
    const int lane = t & 63, w = t >> 6;

    __shared__ float4 tile4[4][65];
    __shared__ float lmin[3][4];
    __shared__ int wsum[4];

    // ---- redundant global min: 24576 float4s as 8192 triplets (4 atoms) ----
    const float4* c4 = reinterpret_cast<const float4*>(coord);
    float mx = FLT_MAX, my = FLT_MAX, mz = FLT_MAX;
    #pragma unroll 4
    for (int k = 0; k < 32; ++k) {
        const int basei = (k * 256 + t) * 3;
        const float4 f0 = c4[basei + 0];
        const float4 f1 = c4[basei + 1];
        const float4 f2 = c4[basei + 2];
        mx = fminf(mx, fminf(fminf(f0.x, f0.w), fminf(f1.z, f2.y)));
        my = fminf(my, fminf(fminf(f0.y, f1.x), fminf(f1.w, f2.z)));
        mz = fminf(mz, fminf(fminf(f0.z, f1.y), fminf(f2.x, f2.w)));
    }
    wave_min3(mx, my, mz);
    if (lane == 0) { lmin[0][w] = mx; lmin[1][w] = my; lmin[2][w] = mz; }
    __syncthreads();
    mx = fminf(fminf(lmin[0][0], lmin[0][1]), fminf(lmin[0][2], lmin[0][3]));
    my = fminf(fminf(lmin[1][0], lmin[1][1]), fminf(lmin[1][2], lmin[1][3]));
    mz = fminf(fminf(lmin[2][0], lmin[2][1]), fminf(lmin[2][2], lmin[2][3]));
    if (b2 == 0 && t == 0) { minvec[0] = mx; minvec[1] = my; minvec[2] = mz; }

    // ---- stage this structure's tile (shifted) ----
    const int ja = b * MM + t;
    tile4[w][lane] = make_float4(__fsub_rn(coord[3 * ja + 0], mx),
                                 __fsub_rn(coord[3 * ja + 1], my),
                                 __fsub_rn(coord[3 * ja + 2], mz), 0.0f);
    __syncthreads();

    // ---- count: hit bitmask ----
    const int i_loc = t >> 2, c = t & 3;
    const float4 pi4 = tile4[rblk][i_loc];
    u64 m = 0ULL;
    for (int jj = 0; jj < 64; ++jj) {
        float4 v = tile4[c][jj];
        float dx = __fsub_rn(v.x, pi4.x);
        float dy = __fsub_rn(v.y, pi4.y);
        float dz = __fsub_rn(v.z, pi4.z);
        float sq = __fadd_rn(__fadd_rn(__fmul_rn(dx, dx), __fmul_rn(dy, dy)),
                             __fmul_rn(dz, dz));
        if (sq > 0.0f && sq <= SQMAX) m |= (1ULL << jj);
    }
    masks[b2 * 256 + t] = m;

    int v = __popcll(m);
    #pragma unroll
    for (int off = 32; off > 0; off >>= 1) v += __shfl_xor(v, off, 64);
    if (lane == 0) wsum[w] = v;
    __syncthreads();
    if (t == 0) bsums[b2] = wsum[0] + wsum[1] + wsum[2] + wsum[3];
}

// K2: wave-0 register scan of 512 bsums -> base/total; staged coalesced
// emission from the saved masks; float4 tail-zero. Output (floats): ind2
// [0,2P) as {gi,gj}, d [2P,3P), df [3P,6P). Pair region + tail partition the
// buffer: every element written exactly once per call.
__global__ void __launch_bounds__(256)
write_k(const float* __restrict__ coord, const float* __restrict__ minvec,
        const u64* __restrict__ masks, const int* __restrict__ bsums,
        float* __restrict__ outF) {
    const int b2 = blockIdx.x;
    const int b = b2 >> 2, rblk = b2 & 3;
    const int t = threadIdx.x;
    const int lane = t & 63, w = t >> 6;

    __shared__ float4 tile4[4][65];
    __shared__ int pre[NBLK];
    __shared__ int sTot;
    __shared__ int wsum[4];
    __shared__ float sd[CAP];        // dist plane
    __shared__ float sind[2 * CAP];  // {gi,gj} plane (as float)
    __shared__ float sdf[3 * CAP];   // {dx,dy,dz} plane

    const float mnx = minvec[0], mny = minvec[1], mnz = minvec[2];
    const int ja = b * MM + t;
    tile4[w][lane] = make_float4(__fsub_rn(coord[3 * ja + 0], mnx),
                                 __fsub_rn(coord[3 * ja + 1], mny),
                                 __fsub_rn(coord[3 * ja + 2], mnz), 0.0f);

    // wave-0 register scan of the 512 block sums (single barrier)
    if (w == 0) {
        int v[8]; int s = 0;
        #pragma unroll
        for (int q = 0; q < 8; ++q) { v[q] = bsums[lane * 8 + q]; s += v[q]; }
        int isum = s;
        #pragma unroll
        for (int off = 1; off < 64; off <<= 1) {
            int u = __shfl_up(isum, off, 64);
            if (lane >= off) isum += u;
        }
        int run = isum - s;                       // exclusive prefix, lane-major
        #pragma unroll
        for (int q = 0; q < 8; ++q) { pre[lane * 8 + q] = run; run += v[q]; }
        if (lane == 63) sTot = run;               // grand total
    }
    __syncthreads();
    const int base = pre[b2];
    const int total = (sTot < PP) ? sTot : PP;

    // per-thread mask -> block-local exclusive offset + block total
    const u64 mask = masks[b2 * 256 + t];
    const int cnt = __popcll(mask);
    int incl = cnt;
    #pragma unroll
    for (int off = 1; off < 64; off <<= 1) {
        int v = __shfl_up(incl, off, 64);
        if (lane >= off) incl += v;
    }
    if (lane == 63) wsum[w] = incl;
    __syncthreads();
    const int agg = wsum[0] + wsum[1] + wsum[2] + wsum[3];
    int woff = 0;
    for (int k = 0; k < w; ++k) woff += wsum[k];
    const int lexcl = woff + incl - cnt;

    const int i_loc = t >> 2, c = t & 3;
    const float4 pi4 = tile4[rblk][i_loc];
    const int gi = b * MM + rblk * 64 + i_loc;
    const int gj0 = b * MM + c * 64;

    // staged, fully-coalesced emission
    const int nbat = (agg + CAP - 1) / CAP;
    for (int bb = 0; bb < nbat; ++bb) {
        const int wlo = bb * CAP, whi = wlo + CAP;
        int q = lexcl;
        u64 mm = mask;
        while (mm) {
            const int jj = __ffsll((long long)mm) - 1;
            mm &= mm - 1;
            if (q >= whi) break;
            if (q >= wlo) {
                float4 v = tile4[c][jj];
                float dx = __fsub_rn(v.x, pi4.x);
                float dy = __fsub_rn(v.y, pi4.y);
                float dz = __fsub_rn(v.z, pi4.z);
                float sq = __fadd_rn(__fadd_rn(__fmul_rn(dx, dx), __fmul_rn(dy, dy)),
                                     __fmul_rn(dz, dz));
                const int s = q - wlo;
                sd[s] = __fsqrt_rn(sq);
                sind[2 * s + 0] = (float)gi;
                sind[2 * s + 1] = (float)(gj0 + jj);
                sdf[3 * s + 0] = dx;
                sdf[3 * s + 1] = dy;
                sdf[3 * s + 2] = dz;
            }
            q++;
        }
        __syncthreads();
        const int nq = ((agg - wlo) < CAP) ? (agg - wlo) : CAP;
        const int pbase = base + wlo;
        int rem = PP - pbase; if (rem < 0) rem = 0;
        const int nv = (nq < rem) ? nq : rem;     // clamp at PP
        for (int k = t; k < nv; k += 256)     outF[2 * PP + pbase + k]     = sd[k];
        for (int k = t; k < 2 * nv; k += 256) outF[2 * pbase + k]          = sind[k];
        for (int k = t; k < 3 * nv; k += 256) outF[3 * PP + 3 * pbase + k] = sdf[k];
        __syncthreads();
    }

    // tail zeroing (disjoint from pair region; coalesced float4)
    const int g = b2 * 256 + t;
    zero_range(outF, 2 * total,          2 * PP, g);
    zero_range(outF, 2 * PP + total,     3 * PP, g);
    zero_range(outF, 3 * PP + 3 * total, 6 * PP, g);
}

extern "C" void kernel_launch(void* const* d_in, const int* in_sizes, int n_in,
                              void* d_out, int out_size, void* d_ws, size_t ws_size,
                              hipStream_t stream) {
    const float* coord = (const float*)d_in[0];
    // d_in[1] (ind_1) structurally encoded (B contiguous blocks of M); unused.
    float* outF = (float*)d_out;

    u64*   masks  = (u64*)d_ws;                    // GTH u64 = 1 MB
    int*   bsums  = (int*)(masks + GTH);           // 512 ints
    float* minvec = (float*)(bsums + NBLK);        // 3 floats

    count_k<<<NBLK, 256, 0, stream>>>(coord, minvec, masks, bsums);
    write_k<<<NBLK, 256, 0, stream>>>(coord, minvec, masks, bsums, outF);
}

// Round 13
// 29.007 us; speedup vs baseline: 4.4845x; 1.0775x over previous
//
#include <hip/hip_runtime.h>
#include <float.h>

#define MM 256
#define PP 2097152            // fixed pair-list length
#define NBLK 512              // 128 structures x 4 row-blocks (write grid)
#define CBLK 256              // count grid: 128 structures x 2 half-blocks
#define GTH (NBLK * 256)
#define CAP 2048              // staged pairs per flush batch
// Largest fp32 sq with rn(sqrt(sq)) < 5.0f  (== 25 - 2*ulp(25); boundary-exact)
#define SQMAX 24.999996185302734375f

typedef unsigned long long u64;

// ws layout: masks u64[GTH] | bsums int[NBLK] | minvec float[3]

__device__ inline void wave_min3(float& x, float& y, float& z) {
    #pragma unroll
    for (int off = 32; off > 0; off >>= 1) {
        x = fminf(x, __shfl_xor(x, off, 64));
        y = fminf(y, __shfl_xor(y, off, 64));
        z = fminf(z, __shfl_xor(z, off, 64));
    }
}

__device__ inline void zero_range(float* __restrict__ o, int lo, int hi, int g) {
    int a = (lo + 3) & ~3;           // hi is always a multiple of 4
    if (a > hi) a = hi;
    if (g < a - lo) o[lo + g] = 0.0f;
    float4* o4 = reinterpret_cast<float4*>(o);
    const float4 z4 = make_float4(0.f, 0.f, 0.f, 0.f);
    for (int q = (a >> 2) + g; q < (hi >> 2); q += GTH) o4[q] = z4;
}

// Bulk float4 flush of an LDS plane to global. gdst is the 16B-aligned base
// (= plane_start - pad); valid elements are [pad, pad+n) in both LDS & global
// (stager wrote with the same pad, so LDS index == global offset mod 4).
__device__ inline void flush_plane(const float* __restrict__ lds, int n, int pad,
                                   float* __restrict__ gdst, int t) {
    if (n <= 0) return;
    const int end = pad + n;
    const int nb = (end + 3) >> 2;
    for (int m = t; m < nb; m += 256) {
        const int lo = m << 2;
        if (lo >= pad && lo + 4 <= end) {
            *reinterpret_cast<float4*>(gdst + lo) =
                *reinterpret_cast<const float4*>(lds + lo);
        } else {
            const int a = lo < pad ? pad : lo;
            const int bmax = (lo + 4 < end) ? (lo + 4) : end;
            for (int e = a; e < bmax; ++e) gdst[e] = lds[e];
        }
    }
}

// ---------------------------------------------------------------------------
// Geometry: virtual slot b2 = b*4+rblk covers rows rblk*64..+64 of structure
// b; slot-thread tt = i_loc*4+c handles (row i_loc, j-chunk c); global slot
// b2*256+tt is lexicographic in (b,i,j). fp32 replicates the reference
// exactly: pos=coord-min (rn sub), diff=pos_j-pos_i, sq=((dx*dx+dy*dy)+dz*dz)
// no-FMA; membership sq<=SQMAX (== rn(sqrt(sq))<5 exactly); d=rn(sqrt) for
// hits only. fmin is exact & order-independent -> matches jnp.min bitwise.
// ---------------------------------------------------------------------------

// K1 (256 blocks x 512 thr): redundant per-block GLOBAL coord min (100 MB L2
// aggregate), then count: hit bitmask -> masks[cb*512+t] (lexicographic),
// per-rowblock totals -> bsums[NBLK]. Block 0 publishes minvec for K2.
__global__ void __launch_bounds__(512)
count_k(const float* __restrict__ coord, float* __restrict__ minvec,
        u64* __restrict__ masks, int* __restrict__ bsums) {
    const int cb = blockIdx.x;           // 0..255: structure b = cb>>1, half = cb&1
    const int b = cb >> 1, h = cb & 1;
    const int t = threadIdx.x;           // 0..511
    const int lane = t & 63, w = t >> 6; // w 0..7

    __shared__ float4 tile4[4][65];
    __shared__ float lmin[3][8];
    __shared__ int wsum[8];

    // ---- redundant global min: 24576 float4 = 8192 triplets (4 atoms each) ----
    const float4* c4 = reinterpret_cast<const float4*>(coord);
    float mx = FLT_MAX, my = FLT_MAX, mz = FLT_MAX;
    #pragma unroll 4
    for (int k = 0; k < 16; ++k) {
        const int basei = (k * 512 + t) * 3;
        const float4 f0 = c4[basei + 0];
        const float4 f1 = c4[basei + 1];
        const float4 f2 = c4[basei + 2];
        mx = fminf(mx, fminf(fminf(f0.x, f0.w), fminf(f1.z, f2.y)));
        my = fminf(my, fminf(fminf(f0.y, f1.x), fminf(f1.w, f2.z)));
        mz = fminf(mz, fminf(fminf(f0.z, f1.y), fminf(f2.x, f2.w)));
    }
    wave_min3(mx, my, mz);
    if (lane == 0) { lmin[0][w] = mx; lmin[1][w] = my; lmin[2][w] = mz; }
    __syncthreads();
    mx = fminf(fminf(fminf(lmin[0][0], lmin[0][1]), fminf(lmin[0][2], lmin[0][3])),
               fminf(fminf(lmin[0][4], lmin[0][5]), fminf(lmin[0][6], lmin[0][7])));
    my = fminf(fminf(fminf(lmin[1][0], lmin[1][1]), fminf(lmin[1][2], lmin[1][3])),
               fminf(fminf(lmin[1][4], lmin[1][5]), fminf(lmin[1][6], lmin[1][7])));
    mz = fminf(fminf(fminf(lmin[2][0], lmin[2][1]), fminf(lmin[2][2], lmin[2][3])),
               fminf(fminf(lmin[2][4], lmin[2][5]), fminf(lmin[2][6], lmin[2][7])));
    if (cb == 0 && t == 0) { minvec[0] = mx; minvec[1] = my; minvec[2] = mz; }

    // ---- stage the whole structure's tile (shifted); threads 0..255 ----
    if (t < 256) {
        const int ja = b * MM + t;
        tile4[t >> 6][t & 63] = make_float4(__fsub_rn(coord[3 * ja + 0], mx),
                                            __fsub_rn(coord[3 * ja + 1], my),
                                            __fsub_rn(coord[3 * ja + 2], mz), 0.0f);
    }
    __syncthreads();

    // ---- count: hit bitmask (slot = cb*512 + t, lexicographic) ----
    const int rblk = 2 * h + (t >> 8);
    const int tt = t & 255;
    const int i_loc = tt >> 2, c = tt & 3;
    const float4 pi4 = tile4[rblk][i_loc];
    u64 m = 0ULL;
    for (int jj = 0; jj < 64; ++jj) {
        float4 v = tile4[c][jj];
        float dx = __fsub_rn(v.x, pi4.x);
        float dy = __fsub_rn(v.y, pi4.y);
        float dz = __fsub_rn(v.z, pi4.z);
        float sq = __fadd_rn(__fadd_rn(__fmul_rn(dx, dx), __fmul_rn(dy, dy)),
                             __fmul_rn(dz, dz));
        if (sq > 0.0f && sq <= SQMAX) m |= (1ULL << jj);
    }
    masks[cb * 512 + t] = m;

    int v = __popcll(m);
    #pragma unroll
    for (int off = 32; off > 0; off >>= 1) v += __shfl_xor(v, off, 64);
    if (lane == 0) wsum[w] = v;
    __syncthreads();
    if (t == 0) {
        bsums[cb * 2 + 0] = wsum[0] + wsum[1] + wsum[2] + wsum[3];
        bsums[cb * 2 + 1] = wsum[4] + wsum[5] + wsum[6] + wsum[7];
    }
}

// K2 (512 blocks x 256 thr): wave-0 register scan of 512 bsums -> base/total;
// staged emission with pad-aligned LDS planes -> float4 bulk flush; float4
// tail-zero. Output (floats): ind2 [0,2P) as {gi,gj}, d [2P,3P), df [3P,6P).
__global__ void __launch_bounds__(256)
write_k(const float* __restrict__ coord, const float* __restrict__ minvec,
        const u64* __restrict__ masks, const int* __restrict__ bsums,
        float* __restrict__ outF) {
    const int b2 = blockIdx.x;
    const int b = b2 >> 2, rblk = b2 & 3;
    const int t = threadIdx.x;
    const int lane = t & 63, w = t >> 6;

    __shared__ float4 tile4[4][65];
    __shared__ int pre[NBLK];
    __shared__ int sTot;
    __shared__ int wsum[4];
    __shared__ __align__(16) float sd[CAP + 4];        // dist plane
    __shared__ __align__(16) float sind[2 * CAP + 4];  // {gi,gj} plane
    __shared__ __align__(16) float sdf[3 * CAP + 4];   // {dx,dy,dz} plane

    const float mnx = minvec[0], mny = minvec[1], mnz = minvec[2];
    const int ja = b * MM + t;
    tile4[w][lane] = make_float4(__fsub_rn(coord[3 * ja + 0], mnx),
                                 __fsub_rn(coord[3 * ja + 1], mny),
                                 __fsub_rn(coord[3 * ja + 2], mnz), 0.0f);

    // wave-0 register scan of the 512 block sums (single barrier)
    if (w == 0) {
        int v[8]; int s = 0;
        #pragma unroll
        for (int q = 0; q < 8; ++q) { v[q] = bsums[lane * 8 + q]; s += v[q]; }
        int isum = s;
        #pragma unroll
        for (int off = 1; off < 64; off <<= 1) {
            int u = __shfl_up(isum, off, 64);
            if (lane >= off) isum += u;
        }
        int run = isum - s;                       // exclusive prefix, lane-major
        #pragma unroll
        for (int q = 0; q < 8; ++q) { pre[lane * 8 + q] = run; run += v[q]; }
        if (lane == 63) sTot = run;               // grand total
    }
    __syncthreads();
    const int base = pre[b2];
    const int total = (sTot < PP) ? sTot : PP;

    // per-thread mask -> block-local exclusive offset + block total
    const u64 mask = masks[b2 * 256 + t];
    const int cnt = __popcll(mask);
    int incl = cnt;
    #pragma unroll
    for (int off = 1; off < 64; off <<= 1) {
        int v = __shfl_up(incl, off, 64);
        if (lane >= off) incl += v;
    }
    if (lane == 63) wsum[w] = incl;
    __syncthreads();
    const int agg = wsum[0] + wsum[1] + wsum[2] + wsum[3];
    int woff = 0;
    for (int k = 0; k < w; ++k) woff += wsum[k];
    const int lexcl = woff + incl - cnt;

    const int i_loc = t >> 2, c = t & 3;
    const float4 pi4 = tile4[rblk][i_loc];
    const int gi = b * MM + rblk * 64 + i_loc;
    const int gj0 = b * MM + c * 64;

    // staged emission; LDS planes pad-aligned so the flush is float4-bulk
    const int nbat = (agg + CAP - 1) / CAP;
    for (int bb = 0; bb < nbat; ++bb) {
        const int wlo = bb * CAP, whi = wlo + CAP;
        const int pbase = base + wlo;             // global pair idx of slot 0
        const int pd = pbase & 3;
        const int pi = (2 * pbase) & 3;
        const int pf = (3 * pbase) & 3;
        int q = lexcl;
        u64 mm = mask;
        while (mm) {
            const int jj = __ffsll((long long)mm) - 1;
            mm &= mm - 1;
            if (q >= whi) break;
            if (q >= wlo) {
                float4 v = tile4[c][jj];
                float dx = __fsub_rn(v.x, pi4.x);
                float dy = __fsub_rn(v.y, pi4.y);
                float dz = __fsub_rn(v.z, pi4.z);
                float sq = __fadd_rn(__fadd_rn(__fmul_rn(dx, dx), __fmul_rn(dy, dy)),
                                     __fmul_rn(dz, dz));
                const int s = q - wlo;
                sd[s + pd] = __fsqrt_rn(sq);
                sind[2 * s + pi + 0] = (float)gi;
                sind[2 * s + pi + 1] = (float)(gj0 + jj);
                sdf[3 * s + pf + 0] = dx;
                sdf[3 * s + pf + 1] = dy;
                sdf[3 * s + pf + 2] = dz;
            }
            q++;
        }
        __syncthreads();
        const int nq = ((agg - wlo) < CAP) ? (agg - wlo) : CAP;
        int rem = PP - pbase; if (rem < 0) rem = 0;
        const int nv = (nq < rem) ? nq : rem;     // clamp at PP
        flush_plane(sd,   nv,     pd, outF + 2 * PP + pbase - pd,     t);
        flush_plane(sind, 2 * nv, pi, outF + 2 * pbase - pi,          t);
        flush_plane(sdf,  3 * nv, pf, outF + 3 * PP + 3 * pbase - pf, t);
        __syncthreads();
    }

    // tail zeroing (disjoint from pair region; coalesced float4)
    const int g = b2 * 256 + t;
    zero_range(outF, 2 * total,          2 * PP, g);
    zero_range(outF, 2 * PP + total,     3 * PP, g);
    zero_range(outF, 3 * PP + 3 * total, 6 * PP, g);
}

extern "C" void kernel_launch(void* const* d_in, const int* in_sizes, int n_in,
                              void* d_out, int out_size, void* d_ws, size_t ws_size,
                              hipStream_t stream) {
    const float* coord = (const float*)d_in[0];
    // d_in[1] (ind_1) structurally encoded (B contiguous blocks of M); unused.
    float* outF = (float*)d_out;

    u64*   masks  = (u64*)d_ws;                    // GTH u64 = 1 MB
    int*   bsums  = (int*)(masks + GTH);           // 512 ints
    float* minvec = (float*)(bsums + NBLK);        // 3 floats

    count_k<<<CBLK, 512, 0, stream>>>(coord, minvec, masks, bsums);
    write_k<<<NBLK, 256, 0, stream>>>(coord, minvec, masks, bsums, outF);
}